// Round 8
// baseline (566.261 us; speedup 1.0000x reference)
//
#include <hip/hip_runtime.h>
#include <stdint.h>

#define BB 8
#define NN 4096

typedef float f32x4 __attribute__((ext_vector_type(4)));
typedef short bf16x8 __attribute__((ext_vector_type(8)));
// may_alias: ALL vector LDS traffic goes through this so the compiler never
// reorders ds_read/ds_write pairs of "different" types (R3-R5 NaN lesson).
typedef bf16x8 bf16x8a __attribute__((may_alias));
#define MFMA16(a, b, c) __builtin_amdgcn_mfma_f32_16x16x32_bf16(a, b, c, 0, 0, 0)

static __device__ __forceinline__ short f2b(float f) {
    unsigned u = __float_as_uint(f);
    unsigned r = (u + 0x7FFFu + ((u >> 16) & 1u)) >> 16;   // RNE, finite values
    return (short)r;
}
static __device__ __forceinline__ float b2f(short s) {
    return __uint_as_float(((unsigned)(unsigned short)s) << 16);
}
static __device__ __forceinline__ bf16x8 pack8(float4 a, float4 b) {
    bf16x8 v;
    v[0] = f2b(a.x); v[1] = f2b(a.y); v[2] = f2b(a.z); v[3] = f2b(a.w);
    v[4] = f2b(b.x); v[5] = f2b(b.y); v[6] = f2b(b.z); v[7] = f2b(b.w);
    return v;
}

// ---------------------------------------------------------------------------
// Prep: pq = (x,y,z,sq); VT = combined edge weight (x | xn folding of W1,
// since edge@W1 = x@(W1a-W1c) + xn@(W1b+W1c)); other weights bf16-transposed.
// ---------------------------------------------------------------------------
__global__ __launch_bounds__(256)
void prep_kernel(const float* __restrict__ pos,
                 const float* __restrict__ W1, const float* __restrict__ W2,
                 const float* __restrict__ Wmid, const float* __restrict__ Wlast,
                 const float* __restrict__ Wg,
                 float4* __restrict__ pq,
                 short* __restrict__ VT, short* __restrict__ W2T,
                 short* __restrict__ WmidT, short* __restrict__ WlastT,
                 short* __restrict__ WgT) {
    int t = blockIdx.x * 256 + threadIdx.x;
    if (t < 32768) {
        float x = pos[t * 3 + 0], y = pos[t * 3 + 1], z = pos[t * 3 + 2];
        float s = __fadd_rn(__fadd_rn(__fmul_rn(x, x), __fmul_rn(y, y)), __fmul_rn(z, z));
        pq[t] = make_float4(x, y, z, s);
    } else if (t < 65536) {          // VT[col*128+k], col<256; k<64: x coef, k>=64: xn coef
        int e = t - 32768; int col = e >> 7, k = e & 127;
        float v;
        if (k < 64) v = W1[(size_t)k * 256 + col] - W1[(size_t)(128 + k) * 256 + col];
        else {
            int j = k - 64;
            v = W1[(size_t)(64 + j) * 256 + col] + W1[(size_t)(128 + j) * 256 + col];
        }
        VT[e] = f2b(v);
    } else if (t < 73728) {          // W2T[col*256+k]
        int e = t - 65536; int col = e >> 8, k = e & 255;
        W2T[e] = f2b(W2[(size_t)k * 32 + col]);
    } else if (t < 76800) {          // WmidT[col*96+k]
        int e = t - 73728; int col = e / 96, k = e - col * 96;
        WmidT[e] = f2b(Wmid[(size_t)k * 32 + col]);
    } else if (t < 80896) {          // WlastT[col*128+k]
        int e = t - 76800; int col = e >> 7, k = e & 127;
        WlastT[e] = f2b(Wlast[(size_t)k * 32 + col]);
    } else if (t < 97280) {          // WgT[col*128+k]
        int e = t - 80896; int col = e >> 7, k = e & 127;
        WgT[e] = f2b(Wg[(size_t)k * 128 + col]);
    }
}

static __device__ __forceinline__ float distf(float4 v, float qx, float qy,
                                              float qz, float qsq) {
    float dot = __fmaf_rn(v.z, qz, __fmaf_rn(v.y, qy, __fmul_rn(v.x, qx)));
    float d = __fsub_rn(__fadd_rn(qsq, v.w), __fmul_rn(2.0f, dot));
    return fmaxf(d, 0.0f);
}

// ---------------------------------------------------------------------------
// Fused v6: KNN (verbatim knn4 body, result stays in registers) + MLP
// pipeline, one point per wave, 4 waves/block. h1 column-split across waves
// with VT (K=128). y's x-part is k-invariant: kept in s_x/s_xg broadcast
// buffers; s_y holds only [mid 0..31 | h2 32..63].
// ---------------------------------------------------------------------------
__global__ __launch_bounds__(256, 3)
void fused6_kernel(const float* __restrict__ x, const float4* __restrict__ pq,
                   const short* __restrict__ VT, const short* __restrict__ W2T,
                   const short* __restrict__ WmidT, const short* __restrict__ WlastT,
                   const short* __restrict__ WgT,
                   const float* __restrict__ b1, const float* __restrict__ b2,
                   const float* __restrict__ bmid, const float* __restrict__ bg,
                   const float* __restrict__ blast,
                   float* __restrict__ out) {
    __shared__ __align__(16) short s_h[64 * 264];   // edge[64][128] then h1[64][256]
    __shared__ __align__(16) short s_y[64 * 72];    // [mid|h2]
    __shared__ __align__(16) short s_x[4][64];      // bf16 x per point (ungated)
    __shared__ __align__(16) short s_xg[4][64];     // bf16 gated x per point
    __shared__ __align__(16) short s_ym[4 * 128];   // bf16 means, row = point
    __shared__ float s_gate[4][128];
    __shared__ unsigned long long comp[4][160];

    const int w = threadIdx.x >> 6;
    const int l = threadIdx.x & 63;
    const int c16 = l & 15;
    const int qa = l >> 4;
    const int p = blockIdx.x * 4 + w;
    const int b = p >> 12;
    const int base = b << 12;
    const float INF = __uint_as_float(0x7F800000u);

    // ===== KNN (knn4 body; lanes 0..15 end holding neighbor ids 1..16) =====
    unsigned keep = 0;
    {
        const float4 self = pq[base + (p & 4095)];
        const float qx = self.x, qy = self.y, qz = self.z, qsq = self.w;

        float lmin = INF;
#pragma unroll 4
        for (int t = 0; t < 64; ++t)
            lmin = fminf(lmin, distf(pq[base + t * 64 + l], qx, qy, qz, qsq));

        float cur = lmin, tau = INF;
        for (int r = 0; r < 17; ++r) {
            float m = cur;
#pragma unroll
            for (int o = 1; o < 64; o <<= 1) m = fminf(m, __shfl_xor(m, o));
            unsigned long long bal = __ballot(cur == m);
            if (l == (__ffsll(bal) - 1)) cur = INF;
            tau = m;
        }

        int cbase = 0;
        const unsigned long long ltm = (l == 0) ? 0ull : ((~0ull) >> (64 - l));
        for (int t = 0; t < 64; ++t) {
            float d = distf(pq[base + t * 64 + l], qx, qy, qz, qsq);
            bool pr = (d <= tau);
            unsigned long long bb = __ballot(pr);
            if (pr) {
                int ps = cbase + __popcll(bb & ltm);
                if (ps < 160)
                    comp[w][ps] = ((unsigned long long)__float_as_uint(d) << 32) |
                                  (unsigned)(t * 64 + l);
            }
            cbase += __popcll(bb);
        }
        if (cbase > 160) cbase = 160;

        const unsigned long long INFK = ~0ull;
        unsigned long long ks[3];
#pragma unroll
        for (int s = 0; s < 3; ++s) {
            int e = s * 64 + l;
            ks[s] = (e < cbase) ? comp[w][e] : INFK;
        }
        for (int r = 0; r < 17; ++r) {
            unsigned long long ml = ks[0];
#pragma unroll
            for (int s = 1; s < 3; ++s) ml = (ks[s] < ml) ? ks[s] : ml;
            unsigned long long g = ml;
#pragma unroll
            for (int o = 1; o < 64; o <<= 1) {
                unsigned long long o2 = __shfl_xor(g, o);
                g = (o2 < g) ? o2 : g;
            }
            unsigned long long bb = __ballot(ml == g);
            if (l == (__ffsll(bb) - 1)) {
                bool done = false;
#pragma unroll
                for (int s = 0; s < 3; ++s)
                    if (!done && ks[s] == g) { ks[s] = INFK; done = true; }
            }
            if (l == r - 1) keep = (unsigned)g;
        }
    }
    const int nb = __shfl((int)keep, c16) & 4095;

    // ===== phase 0: stage [x|xn] to s_h; x to s_x =====
    {
        const float* xrow = x + (size_t)p * 64;
        float4 xa = *(const float4*)(xrow + qa * 8);
        float4 xb = *(const float4*)(xrow + qa * 8 + 4);
        float4 xc = *(const float4*)(xrow + 32 + qa * 8);
        float4 xd = *(const float4*)(xrow + 32 + qa * 8 + 4);
        const float* nrow = x + ((size_t)base + nb) * 64;
        float4 na = *(const float4*)(nrow + qa * 8);
        float4 nb4 = *(const float4*)(nrow + qa * 8 + 4);
        float4 nc = *(const float4*)(nrow + 32 + qa * 8);
        float4 nd = *(const float4*)(nrow + 32 + qa * 8 + 4);
        bf16x8 pxa = pack8(xa, xb), pxc = pack8(xc, xd);
        int row = w * 16 + c16;
        short* sr = s_h + row * 264;
        *(bf16x8a*)(sr + qa * 8)      = pxa;
        *(bf16x8a*)(sr + 32 + qa * 8) = pxc;
        *(bf16x8a*)(sr + 64 + qa * 8) = pack8(na, nb4);
        *(bf16x8a*)(sr + 96 + qa * 8) = pack8(nc, nd);
        if (c16 == 0) {
            *(bf16x8a*)(&s_x[w][qa * 8])      = pxa;
            *(bf16x8a*)(&s_x[w][32 + qa * 8]) = pxc;
        }
    }
    __syncthreads();                                // B1: edge + s_x ready

    // ===== phase 1a: h1 MFMA, K=128 — wave w owns cols [w*64, w*64+64) =====
    f32x4 acc[4][4];
#pragma unroll
    for (int n = 0; n < 4; ++n) {
        float bv = b1[w * 64 + n * 16 + c16];
#pragma unroll
        for (int m = 0; m < 4; ++m) acc[m][n] = (f32x4){bv, bv, bv, bv};
    }
    {
        const short* w1p = VT + (size_t)(w * 64 + c16) * 128 + qa * 8;
#pragma unroll
        for (int t = 0; t < 4; ++t) {
            bf16x8 av[4], bw[4];
#pragma unroll
            for (int m = 0; m < 4; ++m)
                av[m] = *(const bf16x8a*)(s_h + (m * 16 + c16) * 264 + t * 32 + qa * 8);
#pragma unroll
            for (int n = 0; n < 4; ++n)
                bw[n] = *(const bf16x8a*)(w1p + (size_t)n * 2048 + t * 32);
#pragma unroll
            for (int m = 0; m < 4; ++m)
#pragma unroll
                for (int n = 0; n < 4; ++n)
                    acc[m][n] = MFMA16(av[m], bw[n], acc[m][n]);
        }
    }
    __syncthreads();                                // B2: all edge reads done

    // ===== phase 1b: write h1 (bf16) into s_h cols w*64..w*64+64 =====
#pragma unroll
    for (int m = 0; m < 4; ++m)
#pragma unroll
        for (int n = 0; n < 4; ++n)
#pragma unroll
            for (int r = 0; r < 4; ++r)
                s_h[(m * 16 + qa * 4 + r) * 264 + w * 64 + n * 16 + c16] =
                    f2b(fmaxf(acc[m][n][r], 0.f));
    __syncthreads();                                // B3: full h1 ready

    // ===== phase 2: h2 (own point, K=256) -> s_y cols 32..63 =====
    {
        f32x4 hacc[2];
        float h0 = b2[c16], h1v = b2[16 + c16];
        hacc[0] = (f32x4){h0, h0, h0, h0};
        hacc[1] = (f32x4){h1v, h1v, h1v, h1v};
#pragma unroll
        for (int t = 0; t < 8; ++t) {
            bf16x8 am = *(const bf16x8a*)(s_h + (w * 16 + c16) * 264 + t * 32 + qa * 8);
            bf16x8 wb0 = *(const bf16x8a*)(W2T + (size_t)c16 * 256 + t * 32 + qa * 8);
            bf16x8 wb1 = *(const bf16x8a*)(W2T + (size_t)(16 + c16) * 256 + t * 32 + qa * 8);
            hacc[0] = MFMA16(am, wb0, hacc[0]);
            hacc[1] = MFMA16(am, wb1, hacc[1]);
        }
#pragma unroll
        for (int n2 = 0; n2 < 2; ++n2)
#pragma unroll
            for (int r = 0; r < 4; ++r)
                s_y[(w * 16 + qa * 4 + r) * 72 + 32 + n2 * 16 + c16] =
                    f2b(fmaxf(hacc[n2][r], 0.f));
    }

    // ===== phase 3: mid (own point, K=96 over [h2|x]) -> s_y cols 0..31 =====
    {
        f32x4 macc[2];
        float m0 = bmid[c16], m1 = bmid[16 + c16];
        macc[0] = (f32x4){m0, m0, m0, m0};
        macc[1] = (f32x4){m1, m1, m1, m1};
#pragma unroll
        for (int t = 0; t < 3; ++t) {
            bf16x8 av;
            if (t == 0)      av = *(const bf16x8a*)(s_y + (w * 16 + c16) * 72 + 32 + qa * 8);
            else if (t == 1) av = *(const bf16x8a*)(&s_x[w][qa * 8]);
            else             av = *(const bf16x8a*)(&s_x[w][32 + qa * 8]);
            bf16x8 wb0 = *(const bf16x8a*)(WmidT + (size_t)c16 * 96 + t * 32 + qa * 8);
            bf16x8 wb1 = *(const bf16x8a*)(WmidT + (size_t)(16 + c16) * 96 + t * 32 + qa * 8);
            macc[0] = MFMA16(av, wb0, macc[0]);
            macc[1] = MFMA16(av, wb1, macc[1]);
        }
#pragma unroll
        for (int n2 = 0; n2 < 2; ++n2)
#pragma unroll
            for (int r = 0; r < 4; ++r)
                s_y[(w * 16 + qa * 4 + r) * 72 + n2 * 16 + c16] =
                    f2b(fmaxf(macc[n2][r], 0.f));
    }
    __syncthreads();                                // B3b: mid+h2 fully written

    // ===== phase 4: ym = mean over k (mid|h2) + copy x part (k-invariant) ====
    {
        float s0 = 0.f;
#pragma unroll
        for (int k = 0; k < 16; ++k) s0 += b2f(s_y[(w * 16 + k) * 72 + l]);
        s_ym[w * 128 + l]      = f2b(s0 * 0.0625f);
        s_ym[w * 128 + 64 + l] = s_x[w][l];
    }
    __syncthreads();                                // B4: all 4 points' ym ready

    // ===== phase 5: gate — one M-tile (rows=points), wave w owns cols w*32.. =
    {
        f32x4 gacc[2];
        float g0 = bg[w * 32 + c16], g1 = bg[w * 32 + 16 + c16];
        gacc[0] = (f32x4){g0, g0, g0, g0};
        gacc[1] = (f32x4){g1, g1, g1, g1};
#pragma unroll
        for (int t = 0; t < 4; ++t) {
            bf16x8 av = *(const bf16x8a*)(s_ym + (c16 & 3) * 128 + t * 32 + qa * 8);
            bf16x8 wb0 = *(const bf16x8a*)(WgT + (size_t)(w * 32 + c16) * 128 + t * 32 + qa * 8);
            bf16x8 wb1 = *(const bf16x8a*)(WgT + (size_t)(w * 32 + 16 + c16) * 128 + t * 32 + qa * 8);
            gacc[0] = MFMA16(av, wb0, gacc[0]);
            gacc[1] = MFMA16(av, wb1, gacc[1]);
        }
        if (qa == 0) {
#pragma unroll
            for (int n2 = 0; n2 < 2; ++n2)
#pragma unroll
                for (int r = 0; r < 4; ++r)
                    s_gate[r][w * 32 + n2 * 16 + c16] =
                        1.0f / (1.0f + __expf(-gacc[n2][r]));
        }
    }
    __syncthreads();                                // B5: gates ready

    // ===== phase 6: gate y (in place) + y-max; x part is one value/channel ===
    {
        float gy = s_gate[w][l];
        float m0 = -INF;
#pragma unroll
        for (int k = 0; k < 16; ++k) {
            short* yp = s_y + (w * 16 + k) * 72 + l;
            float v = b2f(*yp) * gy;
            m0 = fmaxf(m0, v);
            *yp = f2b(v);
        }
        out[(size_t)p * 160 + 32 + l] = m0;
        float gx = s_gate[w][64 + l];
        float xv = b2f(s_x[w][l]) * gx;
        out[(size_t)p * 160 + 96 + l] = xv;        // max over k of identical values
        s_xg[w][l] = f2b(xv);
    }
    __syncthreads();                                // B6: gated y + s_xg ready

    // ===== phase 7: z = y_gated @ Wlast + blast; max over k; out ch 0..31 ====
    {
        f32x4 zacc[2];
        float z0 = blast[c16], z1 = blast[16 + c16];
        zacc[0] = (f32x4){z0, z0, z0, z0};
        zacc[1] = (f32x4){z1, z1, z1, z1};
#pragma unroll
        for (int t = 0; t < 4; ++t) {
            bf16x8 av;
            if (t == 0)      av = *(const bf16x8a*)(s_y + (w * 16 + c16) * 72 + qa * 8);
            else if (t == 1) av = *(const bf16x8a*)(s_y + (w * 16 + c16) * 72 + 32 + qa * 8);
            else if (t == 2) av = *(const bf16x8a*)(&s_xg[w][qa * 8]);
            else             av = *(const bf16x8a*)(&s_xg[w][32 + qa * 8]);
            bf16x8 wb0 = *(const bf16x8a*)(WlastT + (size_t)c16 * 128 + t * 32 + qa * 8);
            bf16x8 wb1 = *(const bf16x8a*)(WlastT + (size_t)(16 + c16) * 128 + t * 32 + qa * 8);
            zacc[0] = MFMA16(av, wb0, zacc[0]);
            zacc[1] = MFMA16(av, wb1, zacc[1]);
        }
#pragma unroll
        for (int nt = 0; nt < 2; ++nt) {
            float m = fmaxf(fmaxf(zacc[nt][0], zacc[nt][1]),
                            fmaxf(zacc[nt][2], zacc[nt][3]));
            m = fmaxf(m, __shfl_xor(m, 16));
            m = fmaxf(m, __shfl_xor(m, 32));
            if (l < 16) out[(size_t)p * 160 + nt * 16 + l] = m;
        }
    }
}

extern "C" void kernel_launch(void* const* d_in, const int* in_sizes, int n_in,
                              void* d_out, int out_size, void* d_ws, size_t ws_size,
                              hipStream_t stream) {
    const float* x     = (const float*)d_in[0];
    const float* pos   = (const float*)d_in[1];
    const float* W1    = (const float*)d_in[2];
    const float* b1    = (const float*)d_in[3];
    const float* W2    = (const float*)d_in[4];
    const float* b2    = (const float*)d_in[5];
    const float* Wmid  = (const float*)d_in[6];
    const float* bmid  = (const float*)d_in[7];
    const float* Wg    = (const float*)d_in[8];
    const float* bg    = (const float*)d_in[9];
    const float* Wlast = (const float*)d_in[10];
    const float* blast = (const float*)d_in[11];
    float* out = (float*)d_out;

    char* ws = (char*)d_ws;
    float4* pq     = (float4*)(ws + 0);           // 524,288 B
    short*  VT     = (short*)(ws + 524288);       // 65,536 B
    short*  W2T    = (short*)(ws + 589824);       // 16,384 B
    short*  WmidT  = (short*)(ws + 606208);       // 6,144 B
    short*  WlastT = (short*)(ws + 612352);       // 8,192 B
    short*  WgT    = (short*)(ws + 620544);       // 32,768 B

    prep_kernel<<<dim3(380), dim3(256), 0, stream>>>(
        pos, W1, W2, Wmid, Wlast, Wg, pq, VT, W2T, WmidT, WlastT, WgT);
    fused6_kernel<<<dim3(BB * NN / 4), dim3(256), 0, stream>>>(
        x, pq, VT, W2T, WmidT, WlastT, WgT, b1, b2, bmid, bg, blast, out);
}